// Round 1
// baseline (689.820 us; speedup 1.0000x reference)
//
#include <hip/hip_runtime.h>
#include <math.h>

// SwitchMOE: B=8,T=2048,D=1024,F=4096,E=16 ; capacity=1280, K=13
// R5 (polish): router occupancy + E1/E2 load-issue restructure.
//  - router: 512 blocks (2/CU, 8 waves/CU, was 1 block/CU); Wr read straight
//    from L1/L2 (64KB hot) - no LDS staging, no main-loop barriers (was 32).
//  - E1: x hoisted to 4 regs per s (halves VMEM issue); 16 W-loads of the
//    4-row group batched (16KB in flight/wave); 4 butterflies interleaved;
//    h written as one float4.
//  - E2: h staged once per block into LDS (kills 3/4 of h L2 traffic and all
//    h VMEM issue in the dot loop); 2 d-rows per wave share hs reads.

#define TOKENS 16384
#define DD     1024
#define FF     4096
#define EE     16
#define CAP    1280
#define KMAX   13
#define NBLK   512   // router/hist blocks, 32 tokens each

// ---------------------------------------------------------------- router ----
// 512 blocks x 256 thr; 32 tokens/block, 8 per wave (2 groups of 4).
// Wr (64KB) read directly per e-row chunk: L1-hot after first touch.
__global__ __launch_bounds__(256) void router_kernel(
    const float* __restrict__ x, const float* __restrict__ Wr,
    int* __restrict__ top1, float* __restrict__ top1p,
    int* __restrict__ blockhist, float* __restrict__ blockpsum)
{
    __shared__ float p_acc[EE];
    __shared__ int   hist[EE];

    const int tid  = threadIdx.x;
    const int wave = tid >> 6;
    const int lane = tid & 63;
    const int blk  = blockIdx.x;

    if (tid < EE) { p_acc[tid] = 0.0f; hist[tid] = 0; }
    __syncthreads();

    const float4* Wr4 = (const float4*)Wr;
    for (int it = 0; it < 2; ++it) {
        const int tbase = blk * 32 + wave * 8 + it * 4;
        const float4* xp0 = (const float4*)(x + (size_t)(tbase + 0) * DD);
        const float4* xp1 = (const float4*)(x + (size_t)(tbase + 1) * DD);
        const float4* xp2 = (const float4*)(x + (size_t)(tbase + 2) * DD);
        const float4* xp3 = (const float4*)(x + (size_t)(tbase + 3) * DD);

        float acc[4][EE];
        #pragma unroll
        for (int t = 0; t < 4; ++t)
            #pragma unroll
            for (int e = 0; e < EE; ++e) acc[t][e] = 0.0f;

        #pragma unroll
        for (int j = 0; j < 4; ++j) {
            const float4 x0 = xp0[j * 64 + lane];
            const float4 x1 = xp1[j * 64 + lane];
            const float4 x2 = xp2[j * 64 + lane];
            const float4 x3 = xp3[j * 64 + lane];
            #pragma unroll
            for (int e = 0; e < EE; ++e) {
                const float4 w = Wr4[e * 256 + j * 64 + lane];
                acc[0][e] += x0.x*w.x + x0.y*w.y + x0.z*w.z + x0.w*w.w;
                acc[1][e] += x1.x*w.x + x1.y*w.y + x1.z*w.z + x1.w*w.w;
                acc[2][e] += x2.x*w.x + x2.y*w.y + x2.z*w.z + x2.w*w.w;
                acc[3][e] += x3.x*w.x + x3.y*w.y + x3.z*w.z + x3.w*w.w;
            }
        }

        // butterfly reduce: every lane ends with all totals
        #pragma unroll
        for (int t = 0; t < 4; ++t)
            #pragma unroll
            for (int e = 0; e < EE; ++e) {
                float v = acc[t][e];
                v += __shfl_xor(v, 32);
                v += __shfl_xor(v, 16);
                v += __shfl_xor(v, 8);
                v += __shfl_xor(v, 4);
                v += __shfl_xor(v, 2);
                v += __shfl_xor(v, 1);
                acc[t][e] = v;
            }

        if (lane < 4) {
            float lg[EE];
            #pragma unroll
            for (int e = 0; e < EE; ++e) {
                float v = acc[3][e];
                if (lane == 2) v = acc[2][e];
                if (lane == 1) v = acc[1][e];
                if (lane == 0) v = acc[0][e];
                lg[e] = v;
            }
            const int gt = tbase + lane;
            float mx = lg[0]; int bi = 0;
            #pragma unroll
            for (int e = 1; e < EE; ++e)
                if (lg[e] > mx) { mx = lg[e]; bi = e; }   // first-max like argmax
            float pr[EE];
            float s = 0.0f;
            #pragma unroll
            for (int e = 0; e < EE; ++e) { pr[e] = expf(lg[e] - mx); s += pr[e]; }
            const float inv = 1.0f / s;
            top1[gt]  = bi;
            top1p[gt] = inv;                 // = exp(0)/s = max prob
            #pragma unroll
            for (int e = 0; e < EE; ++e) atomicAdd(&p_acc[e], pr[e] * inv);
            atomicAdd(&hist[bi], 1);
        }
    }
    __syncthreads();
    if (tid < EE) {
        blockhist[blk * EE + tid] = hist[tid];
        blockpsum[blk * EE + tid] = p_acc[tid];
    }
}

// ------------------------------------------------------------------ scan ----
// single block: exclusive prefix of blockhist over 512 blocks per expert,
// n_kept, token-0 fill multiplicity, lb_loss (reducing blockpsum).
__global__ __launch_bounds__(256) void scan_kernel(
    const int* __restrict__ blockhist, const float* __restrict__ blockpsum,
    int* __restrict__ base, int* __restrict__ nkept,
    const int* __restrict__ top1, float* __restrict__ mult0,
    float* __restrict__ lb_out)
{
    __shared__ int   hist_l[NBLK * EE];   // 32 KB
    __shared__ int   gsum[EE * 16];
    __shared__ float fps[EE * 16];
    __shared__ float fp[EE];
    __shared__ int   nk_l[EE];

    const int tid = threadIdx.x;
    for (int i = tid; i < NBLK * EE; i += 256) hist_l[i] = blockhist[i];
    __syncthreads();

    const int e = tid >> 4, g = tid & 15;   // 16 experts x 16 groups of 32 blocks
    int s = 0;
    float sp = 0.0f;
    for (int b = g * 32; b < g * 32 + 32; ++b) {
        s  += hist_l[b * EE + e];
        sp += blockpsum[b * EE + e];
    }
    gsum[e * 16 + g] = s;
    fps[e * 16 + g]  = sp;
    __syncthreads();

    int pre = 0;
    for (int g2 = 0; g2 < g; ++g2) pre += gsum[e * 16 + g2];
    int run = pre;
    for (int b = g * 32; b < g * 32 + 32; ++b) {
        base[b * EE + e] = run;
        run += hist_l[b * EE + e];
    }
    if (g == 15) {
        const int c = run;                      // total count for expert e
        const int nk = (c > 0) ? ((c - 1) / CAP + 1) : 0;
        nkept[e] = nk;
        nk_l[e]  = nk;
        float ps = 0.0f;
        for (int g2 = 0; g2 < 16; ++g2) ps += fps[e * 16 + g2];
        fp[e] = ((float)c / (float)TOKENS) * (ps / (float)TOKENS);
    }
    __syncthreads();
    if (tid == 0) {
        const int e0 = top1[0];
        mult0[0] = (float)(1 + KMAX - nk_l[e0]);  // token-0 fill multiplicity
        float sum = 0.0f;
        for (int i = 0; i < EE; ++i) sum += fp[i];
        lb_out[0] = (float)EE * sum * 0.01f;
    }
}

// ------------------------------------------------------------------ keep ----
// per 64-token block: within-32-token-subblock rank recount -> kept-slot list
// + full slotmap write (hist blocks are 32 tokens now).
__global__ __launch_bounds__(64) void keep_kernel(
    const int* __restrict__ top1, const float* __restrict__ top1p,
    const int* __restrict__ base, const float* __restrict__ mult0,
    int* __restrict__ kept_tok, float* __restrict__ kept_scale,
    int* __restrict__ slotmap)
{
    __shared__ int t1[64];
    const int tid = threadIdx.x;
    const int blk = blockIdx.x;
    const int gt  = blk * 64 + tid;
    const int e   = top1[gt];
    t1[tid] = e;
    __syncthreads();
    const int start = tid & 32;               // 32-token sub-block boundary
    int r = 0;
    for (int i = start; i < tid; ++i) r += (t1[i] == e) ? 1 : 0;
    const int hb   = gt >> 5;                 // 32-token hist block index
    const int rank = base[hb * EE + e] + r;
    int sm = -1;
    if (rank % CAP == 0) {
        const int slot = rank / CAP;          // kth kept token has rank k*CAP
        sm = e * KMAX + slot;
        kept_tok[sm] = gt;
        float sc = top1p[gt];
        if (gt == 0) sc *= mult0[0];          // fold fill-slot multiplicity
        kept_scale[sm] = sc;
    }
    slotmap[gt] = sm;
}

// ------------------------------------------------------------------- E1 -----
// h[e][s][f] = gelu(W1[e,f,:] . x[t_s] + b1[e,f]).
// grid EE*256, wave = 4 f-rows: x hoisted to 4 regs per s, all 16 W-loads of
// the row group batched (16KB in flight per wave), 4 interleaved butterflies,
// float4 h write.
__global__ __launch_bounds__(256) void expert1_kernel(
    const float* __restrict__ x, const float* __restrict__ W1,
    const float* __restrict__ b1, const int* __restrict__ nkept,
    const int* __restrict__ kept_tok, float* __restrict__ h)
{
    const int e    = blockIdx.x >> 8;
    const int fblk = blockIdx.x & 255;
    const int ne   = nkept[e];
    if (ne == 0) return;
    const int wave = threadIdx.x >> 6;
    const int lane = threadIdx.x & 63;
    const int f0   = fblk * 16 + wave * 4;
    const float4* wr0 = (const float4*)(W1 + ((size_t)e * FF + f0) * DD);

    for (int s = 0; s < ne; ++s) {
        const int t = kept_tok[e * KMAX + s];
        const float4* xp = (const float4*)(x + (size_t)t * DD);
        float4 xv[4];
        #pragma unroll
        for (int k = 0; k < 4; ++k) xv[k] = xp[k * 64 + lane];

        float4 wv[4][4];
        #pragma unroll
        for (int i = 0; i < 4; ++i)
            #pragma unroll
            for (int k = 0; k < 4; ++k)
                wv[i][k] = wr0[i * 256 + k * 64 + lane];

        float d[4];
        #pragma unroll
        for (int i = 0; i < 4; ++i) {
            float acc = 0.0f;
            #pragma unroll
            for (int k = 0; k < 4; ++k) {
                acc += wv[i][k].x * xv[k].x + wv[i][k].y * xv[k].y
                     + wv[i][k].z * xv[k].z + wv[i][k].w * xv[k].w;
            }
            d[i] = acc;
        }

        // 4 independent butterflies, interleaved to hide shfl latency
        #pragma unroll
        for (int off = 32; off >= 1; off >>= 1) {
            #pragma unroll
            for (int i = 0; i < 4; ++i) d[i] += __shfl_xor(d[i], off);
        }

        if (lane == 0) {
            const float* bp = b1 + e * FF + f0;
            float4 hv;
            {
                const float v = d[0] + bp[0];
                hv.x = 0.5f * v * (1.0f + erff(v * 0.70710678118654752440f));
            }
            {
                const float v = d[1] + bp[1];
                hv.y = 0.5f * v * (1.0f + erff(v * 0.70710678118654752440f));
            }
            {
                const float v = d[2] + bp[2];
                hv.z = 0.5f * v * (1.0f + erff(v * 0.70710678118654752440f));
            }
            {
                const float v = d[3] + bp[3];
                hv.w = 0.5f * v * (1.0f + erff(v * 0.70710678118654752440f));
            }
            *(float4*)(h + ((size_t)e * KMAX + s) * FF + f0) = hv;
        }
    }
}

// ------------------------------------------------------------------- E2 -----
// eo[e][s][d] = scale * (W2[e,d,:] . h[e][s][:] + b2[e,d]).
// grid EE*128 (8 blocks/CU, one round), h staged ONCE per block into LDS
// (16KB), wave = 2 d-rows sharing the hs reads -> VMEM issue is W2-only.
__global__ __launch_bounds__(256) void expert2_kernel(
    const float* __restrict__ h, const float* __restrict__ W2,
    const float* __restrict__ b2, const int* __restrict__ nkept,
    const float* __restrict__ kept_scale, float* __restrict__ eo)
{
    __shared__ float hs[FF];   // 16 KB
    const int e    = blockIdx.x >> 7;
    const int dblk = blockIdx.x & 127;
    const int ne   = nkept[e];
    if (ne == 0) return;
    const int tid  = threadIdx.x;
    const int wave = tid >> 6;
    const int lane = tid & 63;
    const int d0   = dblk * 8 + wave * 2;

    const float4* wr0 = (const float4*)(W2 + ((size_t)e * DD + d0) * FF);
    for (int s = 0; s < ne; ++s) {
        __syncthreads();   // protect hs from previous iteration readers
        const float4* hp = (const float4*)(h + ((size_t)e * KMAX + s) * FF);
        #pragma unroll
        for (int q = 0; q < 4; ++q)
            ((float4*)hs)[q * 256 + tid] = hp[q * 256 + tid];
        __syncthreads();

        float a0 = 0.0f, a1 = 0.0f;
        #pragma unroll
        for (int k = 0; k < 16; ++k) {
            const float4 w0 = wr0[k * 64 + lane];
            const float4 w1 = wr0[1024 + k * 64 + lane];   // row d0+1
            const float4 hv = ((const float4*)hs)[k * 64 + lane];
            a0 += w0.x*hv.x + w0.y*hv.y + w0.z*hv.z + w0.w*hv.w;
            a1 += w1.x*hv.x + w1.y*hv.y + w1.z*hv.z + w1.w*hv.w;
        }
        #pragma unroll
        for (int off = 32; off >= 1; off >>= 1) {
            a0 += __shfl_xor(a0, off);
            a1 += __shfl_xor(a1, off);
        }
        if (lane == 0) {
            const float sc = kept_scale[e * KMAX + s];
            float* ep = eo + ((size_t)e * KMAX + s) * DD + d0;
            ep[0] = sc * (a0 + b2[e * DD + d0]);
            ep[1] = sc * (a1 + b2[e * DD + d0 + 1]);
        }
    }
}

// ---------------------------------------------------------------- expand ----
// single coalesced pass writing the full output (zeros or scattered eo rows;
// scale+bias already folded into eo by E2).
__global__ __launch_bounds__(256) void expand_kernel(
    const float* __restrict__ eo, const int* __restrict__ slotmap,
    float* __restrict__ out)
{
    const int nf4 = TOKENS * DD / 4;            // 4194304 float4
    int idx = blockIdx.x * 256 + threadIdx.x;
    const int stride = 4096 * 256;
    for (; idx < nf4; idx += stride) {
        const int t    = idx >> 8;              // 256 float4 per token
        const int slot = slotmap[t];
        float4 v = make_float4(0.0f, 0.0f, 0.0f, 0.0f);
        if (slot >= 0) v = ((const float4*)eo)[slot * 256 + (idx & 255)];
        ((float4*)out)[idx] = v;
    }
}

// -------------------------------------------------------------- launcher ----
extern "C" void kernel_launch(void* const* d_in, const int* in_sizes, int n_in,
                              void* d_out, int out_size, void* d_ws, size_t ws_size,
                              hipStream_t stream) {
    const float* x  = (const float*)d_in[0];
    const float* Wr = (const float*)d_in[1];
    const float* W1 = (const float*)d_in[2];
    const float* b1 = (const float*)d_in[3];
    const float* W2 = (const float*)d_in[4];
    const float* b2 = (const float*)d_in[5];
    float* out = (float*)d_out;

    char* p = (char*)d_ws;
    int*   top1       = (int*)p;    p += (size_t)TOKENS * 4;
    float* top1p      = (float*)p;  p += (size_t)TOKENS * 4;
    int*   slotmap    = (int*)p;    p += (size_t)TOKENS * 4;
    int*   blockhist  = (int*)p;    p += (size_t)NBLK * EE * 4;
    float* blockpsum  = (float*)p;  p += (size_t)NBLK * EE * 4;
    int*   base       = (int*)p;    p += (size_t)NBLK * EE * 4;
    int*   nkept      = (int*)p;    p += 256;
    float* mult0      = (float*)p;  p += 256;
    int*   kept_tok   = (int*)p;    p += 1024;   // EE*KMAX ints, padded
    float* kept_scale = (float*)p;  p += 1024;
    float* eo         = (float*)p;  p += (size_t)EE * KMAX * DD * 4;
    float* h          = (float*)p;  p += (size_t)EE * KMAX * FF * 4;
    (void)ws_size; (void)in_sizes; (void)n_in;

    router_kernel<<<NBLK, 256, 0, stream>>>(x, Wr, top1, top1p,
                                            blockhist, blockpsum);
    scan_kernel<<<1, 256, 0, stream>>>(blockhist, blockpsum, base, nkept,
                                       top1, mult0, out + (size_t)out_size - 1);
    keep_kernel<<<256, 64, 0, stream>>>(top1, top1p, base, mult0,
                                        kept_tok, kept_scale, slotmap);
    expert1_kernel<<<EE * 256, 256, 0, stream>>>(x, W1, b1, nkept, kept_tok, h);
    expert2_kernel<<<EE * 128, 256, 0, stream>>>(h, W2, b2, nkept, kept_scale, eo);
    expand_kernel<<<4096, 256, 0, stream>>>(eo, slotmap, out);
}